// Round 9
// baseline (171.237 us; speedup 1.0000x reference)
//
#include <hip/hip_runtime.h>
#include <hip/hip_bf16.h>

// Problem constants
#define BB 2
#define TT 2048
#define NX 512
#define NH 4      // 2*H
#define HD 128
#define LL 64
#define KK 32

typedef __bf16 bf16x8 __attribute__((ext_vector_type(8)));
typedef float f32x4 __attribute__((ext_vector_type(4)));
typedef unsigned short us;
typedef const unsigned int __attribute__((address_space(1)))* gptr_t;
typedef unsigned int __attribute__((address_space(3)))* lptr_t;

__device__ __forceinline__ us f2bf(float f) {
    unsigned u = __float_as_uint(f);
    unsigned r = (u + 0x7fffu + ((u >> 16) & 1u)) >> 16;   // RNE
    return (us)r;
}
__device__ __forceinline__ float bf2f(us h) {
    return __uint_as_float(((unsigned)h) << 16);
}

// ---------------------------------------------------------------------------
// Fused: split f32 -> (hi,lo) bf16 for x,wq,wk (hi+lo) and wv,wo (hi only)
// + lam scalars + cs zero
// ---------------------------------------------------------------------------
__global__ void k_split_all(const float* __restrict__ x,
                            const float* __restrict__ wq, const float* __restrict__ wk,
                            const float* __restrict__ wv, const float* __restrict__ wo,
                            us* __restrict__ x_hi, us* __restrict__ x_lo,
                            us* __restrict__ wq_hi, us* __restrict__ wq_lo,
                            us* __restrict__ wk_hi, us* __restrict__ wk_lo,
                            us* __restrict__ wv_hi, us* __restrict__ wo_hi,
                            const float* __restrict__ lq1, const float* __restrict__ lk1,
                            const float* __restrict__ lq2, const float* __restrict__ lk2,
                            const int* __restrict__ lint, float* __restrict__ scal,
                            float* __restrict__ cs)
{
    const int bidx = blockIdx.x;
    if (bidx == 3072) {                       // lam scalars + cs zeroing
        const int tid = threadIdx.x;
        const f32x4 z = {0.f, 0.f, 0.f, 0.f};
        *reinterpret_cast<f32x4*>(cs + tid * 4) = z;   // 1024 floats
        if (tid < 64) {
            float s1 = lq1[tid] * lk1[tid] + lq1[tid + 64] * lk1[tid + 64];
            float s2 = lq2[tid] * lk2[tid] + lq2[tid + 64] * lk2[tid + 64];
            for (int off = 32; off; off >>= 1) { s1 += __shfl_xor(s1, off); s2 += __shfl_xor(s2, off); }
            if (tid == 0) {
                float lam_init = 0.8f - 0.6f * expf(-0.3f * (float)lint[0]);
                scal[0] = expf(s1) - expf(s2) + lam_init;
                scal[1] = lam_init;
            }
        }
        return;
    }
    const float* src;
    us* hi;
    us* lo = nullptr;
    int pos;
    if (bidx < 2048) {
        src = x; hi = x_hi; lo = x_lo;
        pos = bidx * 1024 + threadIdx.x * 4;
    } else {
        const int w = (bidx - 2048) >> 8;          // 0..3
        const int p = (bidx - 2048) & 255;
        pos = p * 1024 + threadIdx.x * 4;
        if (w == 0)      { src = wq; hi = wq_hi; lo = wq_lo; }
        else if (w == 1) { src = wk; hi = wk_hi; lo = wk_lo; }
        else if (w == 2) { src = wv; hi = wv_hi; }
        else             { src = wo; hi = wo_hi; }
    }
    const float4 v = *reinterpret_cast<const float4*>(src + pos);
    ushort4 h;
    h.x = f2bf(v.x); h.y = f2bf(v.y); h.z = f2bf(v.z); h.w = f2bf(v.w);
    *reinterpret_cast<ushort4*>(hi + pos) = h;
    if (lo) {
        ushort4 l;
        l.x = f2bf(v.x - bf2f(h.x));
        l.y = f2bf(v.y - bf2f(h.y));
        l.z = f2bf(v.z - bf2f(h.z));
        l.w = f2bf(v.w - bf2f(h.w));
        *reinterpret_cast<ushort4*>(lo + pos) = l;
    }
}

// ---------------------------------------------------------------------------
// V GEMM: vb[i,c] = (x_hi+x_lo)[i,:] . wv_hi[c,:]  (2-term, K'=1024, bf16 out)
// BM=64, BN=128, BK=64, XOR-swizzled LDS (proven round-6 structure).
// ---------------------------------------------------------------------------
__global__ __launch_bounds__(256) void k_gemm_v(
    const us* __restrict__ x_hi, const us* __restrict__ x_lo,
    const us* __restrict__ wv_hi, us* __restrict__ vb)
{
    __shared__ us lsA[64 * 64];
    __shared__ us lsB[128 * 64];
    const int tid = threadIdx.x;
    const int m0 = blockIdx.x * 64, n0 = blockIdx.y * 128;
    const int l = tid & 63, wid = tid >> 6;
    const int wr = (wid >> 1) * 32, wc = (wid & 1) * 64;
    const int lr = l & 15;
    const int lkb = (l >> 4) * 16;
    f32x4 acc[2][4] = {};
    const int r8 = tid >> 3;
    const int swzc8 = (((tid & 7) ^ (r8 & 7)) * 8);

    for (int kt = 0; kt < 16; ++kt) {
        const int seg = kt >> 3;
        const int koff = (kt & 7) * 64;
        const us* ab = (seg == 0 ? x_hi : x_lo) + koff + swzc8;
        const us* bb = wv_hi + koff + swzc8;
        #pragma unroll
        for (int j = 0; j < 2; ++j)
            __builtin_amdgcn_global_load_lds((gptr_t)(ab + (size_t)(m0 + j * 32 + r8) * 512),
                                             (lptr_t)(lsA + j * 2048 + tid * 8), 16, 0, 0);
        #pragma unroll
        for (int j = 0; j < 4; ++j)
            __builtin_amdgcn_global_load_lds((gptr_t)(bb + (size_t)(n0 + j * 32 + r8) * 512),
                                             (lptr_t)(lsB + j * 2048 + tid * 8), 16, 0, 0);
        __syncthreads();
        bf16x8 af[2][2], bfr[4][2];
        #pragma unroll
        for (int m = 0; m < 2; ++m) {
            const int row = wr + m * 16 + lr;
            #pragma unroll
            for (int kk = 0; kk < 2; ++kk) {
                const int cb = (kk * 64 + lkb) ^ ((row & 7) << 4);
                af[m][kk] = *reinterpret_cast<const bf16x8*>((const char*)lsA + row * 128 + cb);
            }
        }
        #pragma unroll
        for (int n = 0; n < 4; ++n) {
            const int row = wc + n * 16 + lr;
            #pragma unroll
            for (int kk = 0; kk < 2; ++kk) {
                const int cb = (kk * 64 + lkb) ^ ((row & 7) << 4);
                bfr[n][kk] = *reinterpret_cast<const bf16x8*>((const char*)lsB + row * 128 + cb);
            }
        }
        #pragma unroll
        for (int kk = 0; kk < 2; ++kk)
            #pragma unroll
            for (int m = 0; m < 2; ++m)
                #pragma unroll
                for (int n = 0; n < 4; ++n)
                    acc[m][n] = __builtin_amdgcn_mfma_f32_16x16x32_bf16(
                        af[m][kk], bfr[n][kk], acc[m][n], 0, 0, 0);
        __syncthreads();
    }

    #pragma unroll
    for (int m = 0; m < 2; ++m) {
        const int row = m0 + wr + m * 16 + (l >> 4) * 4;
        #pragma unroll
        for (int n = 0; n < 4; ++n) {
            const int col = n0 + wc + n * 16 + lr;
            #pragma unroll
            for (int r = 0; r < 4; ++r)
                vb[(size_t)(row + r) * 512 + col] = f2bf(acc[m][n][r]);
        }
    }
}

// ---------------------------------------------------------------------------
// Landmark q/k rows: sqk[b*64+l, 0:512]=q(lm), [512:1024]=k(lm). 3-term split,
// gathered A rows (x at landmark positions). M=128, N=1024. grid (2,8).
// ---------------------------------------------------------------------------
__global__ __launch_bounds__(256) void k_sqk(
    const us* __restrict__ x_hi, const us* __restrict__ x_lo,
    const us* __restrict__ wq_hi, const us* __restrict__ wq_lo,
    const us* __restrict__ wk_hi, const us* __restrict__ wk_lo,
    const int* __restrict__ lmk, float* __restrict__ sqk)
{
    __shared__ us lsA[64 * 64];
    __shared__ us lsB[128 * 64];
    const int tid = threadIdx.x;
    const int bq = blockIdx.x;                 // batch
    const int n0 = blockIdx.y * 128;           // 0..1023
    const us* bhi = (n0 < 512) ? wq_hi : wk_hi;
    const us* blo = (n0 < 512) ? wq_lo : wk_lo;
    const int ncol = n0 & 511;
    const int l = tid & 63, wid = tid >> 6;
    const int wr = (wid >> 1) * 32, wc = (wid & 1) * 64;
    const int lr = l & 15;
    const int lkb = (l >> 4) * 16;
    f32x4 acc[2][4] = {};
    const int r8 = tid >> 3;
    const int swzc8 = (((tid & 7) ^ (r8 & 7)) * 8);

    for (int kt = 0; kt < 24; ++kt) {
        const int seg = kt >> 3;
        const int koff = (kt & 7) * 64;
        const us* ab = (seg < 2 ? x_hi : x_lo) + koff + swzc8;
        const us* bb = (seg == 1 ? blo : bhi) + koff + swzc8;
        #pragma unroll
        for (int j = 0; j < 2; ++j) {
            const int arow = bq * TT + lmk[j * 32 + r8];   // gather landmark row
            __builtin_amdgcn_global_load_lds((gptr_t)(ab + (size_t)arow * 512),
                                             (lptr_t)(lsA + j * 2048 + tid * 8), 16, 0, 0);
        }
        #pragma unroll
        for (int j = 0; j < 4; ++j)
            __builtin_amdgcn_global_load_lds((gptr_t)(bb + (size_t)(ncol + j * 32 + r8) * 512),
                                             (lptr_t)(lsB + j * 2048 + tid * 8), 16, 0, 0);
        __syncthreads();
        bf16x8 af[2][2], bfr[4][2];
        #pragma unroll
        for (int m = 0; m < 2; ++m) {
            const int row = wr + m * 16 + lr;
            #pragma unroll
            for (int kk = 0; kk < 2; ++kk) {
                const int cb = (kk * 64 + lkb) ^ ((row & 7) << 4);
                af[m][kk] = *reinterpret_cast<const bf16x8*>((const char*)lsA + row * 128 + cb);
            }
        }
        #pragma unroll
        for (int n = 0; n < 4; ++n) {
            const int row = wc + n * 16 + lr;
            #pragma unroll
            for (int kk = 0; kk < 2; ++kk) {
                const int cb = (kk * 64 + lkb) ^ ((row & 7) << 4);
                bfr[n][kk] = *reinterpret_cast<const bf16x8*>((const char*)lsB + row * 128 + cb);
            }
        }
        #pragma unroll
        for (int kk = 0; kk < 2; ++kk)
            #pragma unroll
            for (int m = 0; m < 2; ++m)
                #pragma unroll
                for (int n = 0; n < 4; ++n)
                    acc[m][n] = __builtin_amdgcn_mfma_f32_16x16x32_bf16(
                        af[m][kk], bfr[n][kk], acc[m][n], 0, 0, 0);
        __syncthreads();
    }

    #pragma unroll
    for (int m = 0; m < 2; ++m) {
        const int rowl = wr + m * 16 + (l >> 4) * 4;
        #pragma unroll
        for (int n = 0; n < 4; ++n) {
            const int col = n0 + wc + n * 16 + lr;
            #pragma unroll
            for (int r = 0; r < 4; ++r)
                sqk[(size_t)(bq * 64 + rowl + r) * 1024 + col] = acc[m][n][r];
        }
    }
}

// ---------------------------------------------------------------------------
// Normalize landmark rows (heads 1..3 only) -> qn, kn f32 [2][3][64][128]
// with m1/m2 folded. 4 waves/block, 1 (b,hh,l) unit per wave.
// ---------------------------------------------------------------------------
__global__ __launch_bounds__(256) void k_norm(
    const float* __restrict__ sqk, const float* __restrict__ m1,
    const float* __restrict__ m2, float* __restrict__ qn, float* __restrict__ kn)
{
    const int u = blockIdx.x * 4 + (threadIdx.x >> 6);   // 0..383
    const int l = u & 63;
    const int hh = (u >> 6) % 3;
    const int b = u / 192;
    const int h = hh + 1;
    const int d = threadIdx.x & 63;

    const float* qrow = sqk + (size_t)(b * 64 + l) * 1024 + h * HD;
    const float* krow = qrow + 512;
    const float qa = qrow[d], qb = qrow[d + 64];
    const float ka = krow[d], kb = krow[d + 64];
    float sq = qa * qa + qb * qb;
    float sk = ka * ka + kb * kb;
    for (int off = 32; off; off >>= 1) { sq += __shfl_xor(sq, off); sk += __shfl_xor(sk, off); }
    const float invq = rsqrtf(sq) * m1[h * LL + l];
    const float invk = rsqrtf(sk) * m2[h * LL + l];
    const size_t base = ((size_t)(b * 3 + hh) * 64 + l) * HD;
    qn[base + d] = qa * invq;  qn[base + d + 64] = qb * invq;
    kn[base + d] = ka * invk;  kn[base + d + 64] = kb * invk;
}

// ---------------------------------------------------------------------------
// Effective landmark weights (f32 VALU) -> bf16 hi/lo splits.
// z=0: weff = kn[b,hh] (64x128) @ wq[h*128+d, :]  (for w1 = x @ weff^T)
// z=1: weff = qn[b,hh] (64x128) @ wk[h*128+d, :]  (for w2t)
// Layout: weff[b][z][hh][l][512] = rows z*192+hh*64+l of per-b [384][512].
// blk = ((b*2+z)*3+hh)*8 + c8 ; block computes 64x64 chunk.
// ---------------------------------------------------------------------------
__global__ __launch_bounds__(256) void k_weff(
    const float* __restrict__ qn, const float* __restrict__ kn,
    const float* __restrict__ wq, const float* __restrict__ wk,
    us* __restrict__ weff_hi, us* __restrict__ weff_lo)
{
    __shared__ float As[64][128];    // 32 KB
    __shared__ float Ws[128][64];    // 32 KB
    const int blk = blockIdx.x;      // 96
    const int c8 = blk & 7;
    const int t = blk >> 3;          // 0..11
    const int hh = t % 3;
    const int z = (t / 3) & 1;
    const int b = t / 6;
    const int h = hh + 1;
    const int tid = threadIdx.x;

    const float* A = (z ? qn : kn) + (size_t)(b * 3 + hh) * 64 * 128;
    const float* W = (z ? wk : wq) + (size_t)h * 128 * 512 + c8 * 64;

    #pragma unroll
    for (int it = 0; it < 8; ++it) {
        const int f = (it * 256 + tid) * 4;
        *reinterpret_cast<f32x4*>(&As[f >> 7][f & 127]) =
            *reinterpret_cast<const f32x4*>(A + f);
    }
    #pragma unroll
    for (int it = 0; it < 8; ++it) {
        const int f = (it * 256 + tid) * 4;
        const int d = f >> 6, c = f & 63;
        *reinterpret_cast<f32x4*>(&Ws[d][c]) =
            *reinterpret_cast<const f32x4*>(W + (size_t)d * 512 + c);
    }
    __syncthreads();

    const int tx = tid & 15, ty = tid >> 4;
    float acc[4][4] = {};
    for (int d = 0; d < 128; ++d) {
        const float a0 = As[ty * 4 + 0][d], a1 = As[ty * 4 + 1][d];
        const float a2 = As[ty * 4 + 2][d], a3 = As[ty * 4 + 3][d];
        const float w0 = Ws[d][tx * 4 + 0], w1v = Ws[d][tx * 4 + 1];
        const float w2v = Ws[d][tx * 4 + 2], w3 = Ws[d][tx * 4 + 3];
        acc[0][0] += a0 * w0; acc[0][1] += a0 * w1v; acc[0][2] += a0 * w2v; acc[0][3] += a0 * w3;
        acc[1][0] += a1 * w0; acc[1][1] += a1 * w1v; acc[1][2] += a1 * w2v; acc[1][3] += a1 * w3;
        acc[2][0] += a2 * w0; acc[2][1] += a2 * w1v; acc[2][2] += a2 * w2v; acc[2][3] += a2 * w3;
        acc[3][0] += a3 * w0; acc[3][1] += a3 * w1v; acc[3][2] += a3 * w2v; acc[3][3] += a3 * w3;
    }

    const size_t rowbase = (size_t)(b * 384 + z * 192 + hh * 64);
    #pragma unroll
    for (int i = 0; i < 4; ++i) {
        const size_t row = rowbase + ty * 4 + i;
        #pragma unroll
        for (int j = 0; j < 4; ++j) {
            const size_t off = row * 512 + c8 * 64 + tx * 4 + j;
            const float val = acc[i][j];
            const us hv = f2bf(val);
            weff_hi[off] = hv;
            weff_lo[off] = f2bf(val - bf2f(hv));
        }
    }
}

// ---------------------------------------------------------------------------
// w12 GEMM (3-term split, K'=1536) + V colsum grid-packed.
// Blocks 0..191: per b: x[b] (2048x512) @ weff[b]^T (384x512) -> w12.
// w12 layout [b][z][hh][2048][64]. Blocks 192..223: colsum of vb.
// ---------------------------------------------------------------------------
__global__ __launch_bounds__(256) void k_w12_colsum(
    const us* __restrict__ x_hi, const us* __restrict__ x_lo,
    const us* __restrict__ weff_hi, const us* __restrict__ weff_lo,
    float* __restrict__ w12, const us* __restrict__ vb, float* __restrict__ cs)
{
    const int blk = blockIdx.x;
    const int tid = threadIdx.x;
    if (blk >= 192) {                           // ---- colsum ----
        const int c4 = tid * 4;
        const int b = c4 >> 9, c = c4 & 511;
        const int t0 = (blk - 192) * 64;
        const us* p = vb + ((size_t)(b * TT + t0)) * NX + c;
        f32x4 s = {0.f, 0.f, 0.f, 0.f};
        for (int tt = 0; tt < 64; ++tt) {
            const ushort4 u = *reinterpret_cast<const ushort4*>(p + (size_t)tt * NX);
            s[0] += bf2f(u.x); s[1] += bf2f(u.y); s[2] += bf2f(u.z); s[3] += bf2f(u.w);
        }
        atomicAdd(&cs[c4 + 0], s[0]);
        atomicAdd(&cs[c4 + 1], s[1]);
        atomicAdd(&cs[c4 + 2], s[2]);
        atomicAdd(&cs[c4 + 3], s[3]);
        return;
    }
    // ---- w12 GEMM ----
    __shared__ us lsA[64 * 64];
    __shared__ us lsB[128 * 64];
    const int bx = blk & 31;
    const int ny = (blk >> 5) % 3;
    const int b = blk / 96;
    const int m0 = b * TT + bx * 64;            // global x row
    const int n0b = ny * 128;                   // within per-b 384
    const us* bhi = weff_hi + (size_t)b * 384 * 512;
    const us* blo = weff_lo + (size_t)b * 384 * 512;

    const int l = tid & 63, wid = tid >> 6;
    const int wr = (wid >> 1) * 32, wc = (wid & 1) * 64;
    const int lr = l & 15;
    const int lkb = (l >> 4) * 16;
    f32x4 acc[2][4] = {};
    const int r8 = tid >> 3;
    const int swzc8 = (((tid & 7) ^ (r8 & 7)) * 8);

    for (int kt = 0; kt < 24; ++kt) {
        const int seg = kt >> 3;
        const int koff = (kt & 7) * 64;
        const us* ab = (seg < 2 ? x_hi : x_lo) + koff + swzc8;
        const us* bb = (seg == 1 ? blo : bhi) + koff + swzc8;
        #pragma unroll
        for (int j = 0; j < 2; ++j)
            __builtin_amdgcn_global_load_lds((gptr_t)(ab + (size_t)(m0 + j * 32 + r8) * 512),
                                             (lptr_t)(lsA + j * 2048 + tid * 8), 16, 0, 0);
        #pragma unroll
        for (int j = 0; j < 4; ++j)
            __builtin_amdgcn_global_load_lds((gptr_t)(bb + (size_t)(n0b + j * 32 + r8) * 512),
                                             (lptr_t)(lsB + j * 2048 + tid * 8), 16, 0, 0);
        __syncthreads();
        bf16x8 af[2][2], bfr[4][2];
        #pragma unroll
        for (int m = 0; m < 2; ++m) {
            const int row = wr + m * 16 + lr;
            #pragma unroll
            for (int kk = 0; kk < 2; ++kk) {
                const int cb = (kk * 64 + lkb) ^ ((row & 7) << 4);
                af[m][kk] = *reinterpret_cast<const bf16x8*>((const char*)lsA + row * 128 + cb);
            }
        }
        #pragma unroll
        for (int n = 0; n < 4; ++n) {
            const int row = wc + n * 16 + lr;
            #pragma unroll
            for (int kk = 0; kk < 2; ++kk) {
                const int cb = (kk * 64 + lkb) ^ ((row & 7) << 4);
                bfr[n][kk] = *reinterpret_cast<const bf16x8*>((const char*)lsB + row * 128 + cb);
            }
        }
        #pragma unroll
        for (int kk = 0; kk < 2; ++kk)
            #pragma unroll
            for (int m = 0; m < 2; ++m)
                #pragma unroll
                for (int n = 0; n < 4; ++n)
                    acc[m][n] = __builtin_amdgcn_mfma_f32_16x16x32_bf16(
                        af[m][kk], bfr[n][kk], acc[m][n], 0, 0, 0);
        __syncthreads();
    }

    #pragma unroll
    for (int m = 0; m < 2; ++m) {
        const int i = bx * 64 + wr + m * 16 + (l >> 4) * 4;   // row within 2048
        #pragma unroll
        for (int n = 0; n < 4; ++n) {
            const int col = n0b + wc + n * 16 + lr;           // 0..383
            const int z = col / 192;
            const int r2 = col - z * 192;
            const int hh = r2 >> 6, ll = r2 & 63;
            float* C = w12 + (((size_t)((b * 2 + z) * 3 + hh) * TT)) * 64;
            #pragma unroll
            for (int r = 0; r < 4; ++r)
                C[(size_t)(i + r) * 64 + ll] = acc[m][n][r];
        }
    }
}

// ---------------------------------------------------------------------------
// Sparse masked softmax + wmix + PV + RMSNorm. ONE WAVE per (b, row i).
// w12 layout [b][z][hh][T][64]: z=0 -> w1, z=1 -> w2t.
// ---------------------------------------------------------------------------
__global__ __launch_bounds__(256) void k_sparse_attn(
    const float* __restrict__ w12, const us* __restrict__ vb,
    const float* __restrict__ cs, const int* __restrict__ rns,
    const float* __restrict__ rms_g, const float* __restrict__ scal,
    us* __restrict__ ao)
{
    const int wid = threadIdx.x >> 6;
    const int lane = threadIdx.x & 63;
    const int bi = blockIdx.x * 4 + wid;     // 0..4095
    const int b = bi >> 11, i = bi & 2047;

    __shared__ int   sl[4][32];
    __shared__ float plog[4][96];
    __shared__ float wmm[4][2][32];
    __shared__ float w1s[4][3][64];

    // candidates + dedup + symmetric check
    const int myidx = lane & 31;
    const int cand = rns[(size_t)bi * KK + myidx];
    int dup = 0;
    #pragma unroll
    for (int kk = 0; kk < 31; ++kk) {
        const int other = __shfl(cand, kk);
        dup |= (kk < myidx) & (other == cand);
    }
    const int* jrow = rns + ((size_t)(b * TT + cand)) * KK + (lane >> 5) * 16;
    int found = 0;
    #pragma unroll
    for (int kk = 0; kk < 16; ++kk) found |= (jrow[kk] == i);
    found |= __shfl_xor(found, 32);
    const int keep = (!dup) && found;
    const unsigned long long mask = __ballot(keep) & 0xffffffffull;
    const int sc = __popcll(mask);
    const int pos = __popcll(mask & ((1ull << myidx) - 1ull));
    if (lane < 32 && keep) sl[wid][pos] = cand;

    const float lam = scal[0], lam_init = scal[1];
    const float* w1b = w12 + (size_t)(b * 2) * 3 * TT * 64;       // z=0
    const float* w2b = w12 + (size_t)(b * 2 + 1) * 3 * TT * 64;   // z=1

    if (sc > 0) {
        #pragma unroll
        for (int r = 0; r < 3; ++r)
            w1s[wid][r][lane] = w1b[((size_t)r * TT + i) * 64 + lane];
        const int ntask = 3 * sc;
        for (int t0 = 0; t0 < ntask; t0 += 8) {
            const int t = t0 + (lane >> 3);
            float part = 0.f;
            if (t < ntask) {
                const int hh = t % 3, ss = t / 3;
                const int j = sl[wid][ss];
                const float* w2row = w2b + ((size_t)hh * TT + j) * 64 + (lane & 7) * 8;
                const float* w1p = &w1s[wid][hh][(lane & 7) * 8];
                #pragma unroll
                for (int e = 0; e < 8; ++e) part += w1p[e] * w2row[e];
            }
            part += __shfl_xor(part, 1);
            part += __shfl_xor(part, 2);
            part += __shfl_xor(part, 4);
            if (t < ntask && (lane & 7) == 0) plog[wid][t] = part;
        }
        if (lane < 3) {
            float mx = -1e30f;
            for (int ss = 0; ss < sc; ++ss) mx = fmaxf(mx, plog[wid][ss * 3 + lane]);
            float s = 0.f;
            for (int ss = 0; ss < sc; ++ss) {
                const float e = expf(plog[wid][ss * 3 + lane] - mx);
                plog[wid][ss * 3 + lane] = e;
                s += e;
            }
            const float inv = 1.0f / s;
            for (int ss = 0; ss < sc; ++ss) plog[wid][ss * 3 + lane] *= inv;
        }
        if (lane < sc) {
            const float p1 = plog[wid][lane * 3 + 0];
            const float p2 = plog[wid][lane * 3 + 1];
            const float p3 = plog[wid][lane * 3 + 2];
            wmm[wid][0][lane] = (1.0f - lam) * p2 - lam * p1;
            wmm[wid][1][lane] = p2 - p1 + (1.0f - 2.0f * lam) * p3;
        }
    }

    // PV
    f32x4 acc0 = {0.f, 0.f, 0.f, 0.f}, acc1 = {0.f, 0.f, 0.f, 0.f};
    if (sc == 0) {
        const float cc = (1.0f - 2.0f * lam) * (1.0f / (float)TT);
        const f32x4 c0 = *reinterpret_cast<const f32x4*>(cs + b * NX + lane * 4);
        const f32x4 c1 = *reinterpret_cast<const f32x4*>(cs + b * NX + 256 + lane * 4);
        acc0 = cc * c0;
        acc1 = cc * c1;
    } else {
        for (int ss = 0; ss < sc; ++ss) {
            const float wa = wmm[wid][0][ss], wb = wmm[wid][1][ss];
            const us* vrow = vb + ((size_t)(b * TT + sl[wid][ss])) * NX;
            const ushort4 ua = *reinterpret_cast<const ushort4*>(vrow + lane * 4);
            const ushort4 ub = *reinterpret_cast<const ushort4*>(vrow + 256 + lane * 4);
            acc0[0] += wa * bf2f(ua.x); acc0[1] += wa * bf2f(ua.y);
            acc0[2] += wa * bf2f(ua.z); acc0[3] += wa * bf2f(ua.w);
            acc1[0] += wb * bf2f(ub.x); acc1[1] += wb * bf2f(ub.y);
            acc1[2] += wb * bf2f(ub.z); acc1[3] += wb * bf2f(ub.w);
        }
    }

    // RMSNorm per half
    float s0 = acc0[0]*acc0[0] + acc0[1]*acc0[1] + acc0[2]*acc0[2] + acc0[3]*acc0[3];
    float s1 = acc1[0]*acc1[0] + acc1[1]*acc1[1] + acc1[2]*acc1[2] + acc1[3]*acc1[3];
    #pragma unroll
    for (int off = 32; off; off >>= 1) { s0 += __shfl_xor(s0, off); s1 += __shfl_xor(s1, off); }
    const float sc0 = rsqrtf(s0 * (1.0f / 256.0f) + 1e-5f);
    const float sc1 = rsqrtf(s1 * (1.0f / 256.0f) + 1e-5f);
    const float og = 1.0f - lam_init;
    // rms_g (256,) broadcasts over the last axis: BOTH halves use rms_g[e]
    const f32x4 g = *reinterpret_cast<const f32x4*>(rms_g + lane * 4);
    ushort4 h0, h1;
    #pragma unroll
    for (int e = 0; e < 4; ++e) {
        (&h0.x)[e] = f2bf(acc0[e] * sc0 * g[e] * og);
        (&h1.x)[e] = f2bf(acc1[e] * sc1 * g[e] * og);
    }
    *reinterpret_cast<ushort4*>(ao + (size_t)bi * NX + lane * 4) = h0;
    *reinterpret_cast<ushort4*>(ao + (size_t)bi * NX + 256 + lane * 4) = h1;
}

// ---------------------------------------------------------------------------
// Out GEMM: out[i,c] = ao[i,:] . wo_hi[c,:]  (1-seg, K'=512, f32 out)
// BM=64, BN=64. grid (64, 8).
// ---------------------------------------------------------------------------
__global__ __launch_bounds__(256) void k_gemm_out(
    const us* __restrict__ ao, const us* __restrict__ wo_hi, float* __restrict__ out)
{
    __shared__ us lsA[64 * 64];
    __shared__ us lsB[64 * 64];
    const int tid = threadIdx.x;
    const int m0 = blockIdx.x * 64, n0 = blockIdx.y * 64;
    const int l = tid & 63, wid = tid >> 6;
    const int wr = (wid >> 1) * 32, wc = (wid & 1) * 32;
    const int lr = l & 15;
    const int lkb = (l >> 4) * 16;
    f32x4 acc[2][2] = {};
    const int r8 = tid >> 3;
    const int swzc8 = (((tid & 7) ^ (r8 & 7)) * 8);

    for (int kt = 0; kt < 8; ++kt) {
        const int koff = kt * 64;
        const us* ab = ao + koff + swzc8;
        const us* bb = wo_hi + koff + swzc8;
        #pragma unroll
        for (int j = 0; j < 2; ++j) {
            __builtin_amdgcn_global_load_lds((gptr_t)(ab + (size_t)(m0 + j * 32 + r8) * 512),
                                             (lptr_t)(lsA + j * 2048 + tid * 8), 16, 0, 0);
            __builtin_amdgcn_global_load_lds((gptr_t)(bb + (size_t)(n0 + j * 32 + r8) * 512),
                                             (lptr_t)(lsB + j * 2048 + tid * 8), 16, 0, 0);
        }
        __syncthreads();
        bf16x8 af[2][2], bfr[2][2];
        #pragma unroll
        for (int m = 0; m < 2; ++m) {
            const int row = wr + m * 16 + lr;
            #pragma unroll
            for (int kk = 0; kk < 2; ++kk) {
                const int cb = (kk * 64 + lkb) ^ ((row & 7) << 4);
                af[m][kk] = *reinterpret_cast<const bf16x8*>((const char*)lsA + row * 128 + cb);
            }
        }
        #pragma unroll
        for (int n = 0; n < 2; ++n) {
            const int row = wc + n * 16 + lr;
            #pragma unroll
            for (int kk = 0; kk < 2; ++kk) {
                const int cb = (kk * 64 + lkb) ^ ((row & 7) << 4);
                bfr[n][kk] = *reinterpret_cast<const bf16x8*>((const char*)lsB + row * 128 + cb);
            }
        }
        #pragma unroll
        for (int kk = 0; kk < 2; ++kk)
            #pragma unroll
            for (int m = 0; m < 2; ++m)
                #pragma unroll
                for (int n = 0; n < 2; ++n)
                    acc[m][n] = __builtin_amdgcn_mfma_f32_16x16x32_bf16(
                        af[m][kk], bfr[n][kk], acc[m][n], 0, 0, 0);
        __syncthreads();
    }

    #pragma unroll
    for (int m = 0; m < 2; ++m) {
        const int row = m0 + wr + m * 16 + (l >> 4) * 4;
        #pragma unroll
        for (int n = 0; n < 2; ++n) {
            const int col = n0 + wc + n * 16 + lr;
            #pragma unroll
            for (int r = 0; r < 4; ++r)
                out[(size_t)(row + r) * 512 + col] = acc[m][n][r];
        }
    }
}

extern "C" void kernel_launch(void* const* d_in, const int* in_sizes, int n_in,
                              void* d_out, int out_size, void* d_ws, size_t ws_size,
                              hipStream_t stream)
{
    const float* x    = (const float*)d_in[0];
    const float* wq   = (const float*)d_in[1];
    const float* wk   = (const float*)d_in[2];
    const float* wv   = (const float*)d_in[3];
    const float* wo   = (const float*)d_in[4];
    const float* m1   = (const float*)d_in[5];
    const float* m2   = (const float*)d_in[6];
    const float* lq1  = (const float*)d_in[7];
    const float* lk1  = (const float*)d_in[8];
    const float* lq2  = (const float*)d_in[9];
    const float* lk2  = (const float*)d_in[10];
    const float* rmsg = (const float*)d_in[11];
    const int*   lint = (const int*)d_in[12];
    const int*   rns  = (const int*)d_in[14];
    const int*   lmk  = (const int*)d_in[15];
    float* out = (float*)d_out;
    float* ws  = (float*)d_ws;

    // ---- workspace layout (f32 region then us region) ----
    float* w12  = ws;                            // 12*2048*64 = 1,572,864 f32
    float* sqk  = ws + 1572864;                  // 131,072 f32
    float* qn   = sqk + 131072;                  // 49,152 f32
    float* kn   = qn + 49152;                    // 49,152 f32
    float* cs   = kn + 49152;                    // 1,024 f32
    float* scal = cs + 1024;                     // 128 f32 pad
    us* S = (us*)(scal + 128);
    const size_t M2 = 2097152;
    us* vb      = S;                             // 2M us
    us* x_hi    = S + M2;                        // 2M
    us* x_lo    = S + 2 * M2;                    // 2M
    us* ao      = x_hi;                          // reuse (x split dead by then)
    us* wq_hi   = S + 3 * M2;                    // 262,144 each
    us* wq_lo   = wq_hi + 262144;
    us* wk_hi   = wq_lo + 262144;
    us* wk_lo   = wk_hi + 262144;
    us* wv_hi   = wk_lo + 262144;
    us* wo_hi   = wv_hi + 262144;
    us* weff_hi = wo_hi + 262144;                // 393,216 each (2*384*512)
    us* weff_lo = weff_hi + 393216;

    k_split_all<<<3073, 256, 0, stream>>>(x, wq, wk, wv, wo,
                                          x_hi, x_lo, wq_hi, wq_lo, wk_hi, wk_lo,
                                          wv_hi, wo_hi,
                                          lq1, lk1, lq2, lk2, lint, scal, cs);

    // v = x @ wv^T (2-term), bf16 out — independent of the landmark chain
    k_gemm_v<<<dim3(64, 4), 256, 0, stream>>>(x_hi, x_lo, wv_hi, vb);

    // landmark q/k rows (3-term, gathered)
    k_sqk<<<dim3(2, 8), 256, 0, stream>>>(x_hi, x_lo, wq_hi, wq_lo, wk_hi, wk_lo,
                                          lmk, sqk);
    k_norm<<<96, 256, 0, stream>>>(sqk, m1, m2, qn, kn);
    k_weff<<<96, 256, 0, stream>>>(qn, kn, wq, wk, weff_hi, weff_lo);

    // w1/w2t = x @ weff^T (3-term) + V colsum
    k_w12_colsum<<<224, 256, 0, stream>>>(x_hi, x_lo, weff_hi, weff_lo, w12, vb, cs);

    k_sparse_attn<<<1024, 256, 0, stream>>>(w12, vb, cs, rns, rmsg, scal, ao);

    // out = ao @ wo^T (1-seg)
    k_gemm_out<<<dim3(64, 8), 256, 0, stream>>>(ao, wo_hi, out);
}

// Round 11
// 140.756 us; speedup vs baseline: 1.2165x; 1.2165x over previous
//
#include <hip/hip_runtime.h>
#include <hip/hip_bf16.h>

// Problem constants
#define BB 2
#define TT 2048
#define NX 512
#define NH 4      // 2*H
#define HD 128
#define LL 64
#define KK 32

typedef __bf16 bf16x8 __attribute__((ext_vector_type(8)));
typedef float f32x4 __attribute__((ext_vector_type(4)));
typedef unsigned short us;
typedef const unsigned int __attribute__((address_space(1)))* gptr_t;
typedef unsigned int __attribute__((address_space(3)))* lptr_t;

__device__ __forceinline__ us f2bf(float f) {
    unsigned u = __float_as_uint(f);
    unsigned r = (u + 0x7fffu + ((u >> 16) & 1u)) >> 16;   // RNE
    return (us)r;
}
__device__ __forceinline__ float bf2f(us h) {
    return __uint_as_float(((unsigned)h) << 16);
}

// ---------------------------------------------------------------------------
// Fused: split f32 -> (hi,lo) bf16 for x,wq,wk,wv,wo  +  lam scalars + cs zero
// ---------------------------------------------------------------------------
__global__ void k_split_all(const float* __restrict__ x,
                            const float* __restrict__ wq, const float* __restrict__ wk,
                            const float* __restrict__ wv, const float* __restrict__ wo,
                            us* __restrict__ x_hi, us* __restrict__ x_lo,
                            us* __restrict__ wqkv_hi, us* __restrict__ wqkv_lo,
                            us* __restrict__ wo_hi, us* __restrict__ wo_lo,
                            const float* __restrict__ lq1, const float* __restrict__ lk1,
                            const float* __restrict__ lq2, const float* __restrict__ lk2,
                            const int* __restrict__ lint, float* __restrict__ scal,
                            float* __restrict__ cs)
{
    const int bidx = blockIdx.x;
    if (bidx == 3072) {                       // lam scalars + cs zeroing
        const int tid = threadIdx.x;
        const f32x4 z = {0.f, 0.f, 0.f, 0.f};
        *reinterpret_cast<f32x4*>(cs + tid * 4) = z;   // 256*4 = 1024 floats
        if (tid < 64) {
            float s1 = lq1[tid] * lk1[tid] + lq1[tid + 64] * lk1[tid + 64];
            float s2 = lq2[tid] * lk2[tid] + lq2[tid + 64] * lk2[tid + 64];
            for (int off = 32; off; off >>= 1) { s1 += __shfl_xor(s1, off); s2 += __shfl_xor(s2, off); }
            if (tid == 0) {
                float lam_init = 0.8f - 0.6f * expf(-0.3f * (float)lint[0]);
                scal[0] = expf(s1) - expf(s2) + lam_init;
                scal[1] = lam_init;
            }
        }
        return;
    }
    const float* src;
    us* hi;
    us* lo;
    int pos;
    if (bidx < 2048) {
        src = x; hi = x_hi; lo = x_lo;
        pos = bidx * 1024 + threadIdx.x * 4;
    } else {
        const int w = (bidx - 2048) >> 8;          // 0..3
        const int p = (bidx - 2048) & 255;
        pos = p * 1024 + threadIdx.x * 4;
        if (w == 0)      { src = wq; hi = wqkv_hi;          lo = wqkv_lo; }
        else if (w == 1) { src = wk; hi = wqkv_hi + 262144; lo = wqkv_lo + 262144; }
        else if (w == 2) { src = wv; hi = wqkv_hi + 524288; lo = wqkv_lo + 524288; }
        else             { src = wo; hi = wo_hi;            lo = wo_lo; }
    }
    const float4 v = *reinterpret_cast<const float4*>(src + pos);
    ushort4 h, l;
    h.x = f2bf(v.x); l.x = f2bf(v.x - bf2f(h.x));
    h.y = f2bf(v.y); l.y = f2bf(v.y - bf2f(h.y));
    h.z = f2bf(v.z); l.z = f2bf(v.z - bf2f(h.z));
    h.w = f2bf(v.w); l.w = f2bf(v.w - bf2f(h.w));
    *reinterpret_cast<ushort4*>(hi + pos) = h;
    *reinterpret_cast<ushort4*>(lo + pos) = l;
}

// ---------------------------------------------------------------------------
// Split-bf16 MFMA GEMM, BM=64, BK=64, XOR-swizzled LDS, SINGLE buffer
// (stage -> sync -> compute -> sync; proven round-6/8 structure).
// MODE 0 (QKV, BN=128): q/k regions: 3 segs A{hi,hi,lo} B{hi,lo,hi} -> bf16
//   hi/lo splits; v region: 2 segs (a_hi+a_lo).b_hi -> bf16.
// MODE 1 (OUT, BN=64): 1 seg a_hi.b_hi (K'=512), f32 out.
// ---------------------------------------------------------------------------
template<int BN, int MODE>
__global__ __launch_bounds__(256) void k_gemm_big(
    const us* __restrict__ a_hi, const us* __restrict__ a_lo,
    const us* __restrict__ b_hi, const us* __restrict__ b_lo,
    us* __restrict__ vb, float* __restrict__ cout,
    us* __restrict__ qs_hi, us* __restrict__ qs_lo,
    us* __restrict__ ks_hi, us* __restrict__ ks_lo)
{
    constexpr int NB = BN / 32;                 // frag cols per wave
    __shared__ us lsA[64 * 64];
    __shared__ us lsB[BN * 64];
    const int tid = threadIdx.x;
    const int m0 = blockIdx.x * 64, n0 = blockIdx.y * BN;
    const int region = n0 >> 9;                 // 0:q 1:k 2:v (MODE 0)
    const int ncol0 = n0 & 511;
    const int l = tid & 63, wid = tid >> 6;
    const int wr = (wid >> 1) * 32, wc = (wid & 1) * (BN / 2);
    const int lr = l & 15;
    const int lkb = (l >> 4) * 16;              // byte offset of lane's k-octet
    f32x4 acc[2][NB] = {};

    const int r8 = tid >> 3;                    // staging row 0..31
    const int swzc8 = (((tid & 7) ^ (r8 & 7)) * 8);  // pre-swizzled col (shorts)

    const int nstep = (MODE == 0) ? (region < 2 ? 24 : 16) : 8;
    for (int kt = 0; kt < nstep; ++kt) {
        const int seg = kt >> 3;
        const int koff = (kt & 7) * 64;
        const us* ab;
        const us* bb;
        if constexpr (MODE == 0) {
            if (region < 2) {
                ab = (seg < 2 ? a_hi : a_lo) + koff + swzc8;
                bb = (seg == 1 ? b_lo : b_hi) + koff + swzc8;
            } else {   // v: (a_hi + a_lo) . b_hi
                ab = (seg == 0 ? a_hi : a_lo) + koff + swzc8;
                bb = b_hi + koff + swzc8;
            }
        } else {       // out: a_hi . b_hi only
            ab = a_hi + koff + swzc8;
            bb = b_hi + koff + swzc8;
        }
        #pragma unroll
        for (int j = 0; j < 2; ++j)
            __builtin_amdgcn_global_load_lds((gptr_t)(ab + (size_t)(m0 + j * 32 + r8) * 512),
                                             (lptr_t)(lsA + j * 2048 + tid * 8), 16, 0, 0);
        #pragma unroll
        for (int j = 0; j < BN / 32; ++j)
            __builtin_amdgcn_global_load_lds((gptr_t)(bb + (size_t)(n0 + j * 32 + r8) * 512),
                                             (lptr_t)(lsB + j * 2048 + tid * 8), 16, 0, 0);
        __syncthreads();   // barrier drains vmcnt -> LDS writes visible
        bf16x8 af[2][2], bfr[NB][2];
        #pragma unroll
        for (int m = 0; m < 2; ++m) {
            const int row = wr + m * 16 + lr;
            #pragma unroll
            for (int kk = 0; kk < 2; ++kk) {
                const int cb = (kk * 64 + lkb) ^ ((row & 7) << 4);
                af[m][kk] = *reinterpret_cast<const bf16x8*>(
                    (const char*)lsA + row * 128 + cb);
            }
        }
        #pragma unroll
        for (int n = 0; n < NB; ++n) {
            const int row = wc + n * 16 + lr;
            #pragma unroll
            for (int kk = 0; kk < 2; ++kk) {
                const int cb = (kk * 64 + lkb) ^ ((row & 7) << 4);
                bfr[n][kk] = *reinterpret_cast<const bf16x8*>(
                    (const char*)lsB + row * 128 + cb);
            }
        }
        #pragma unroll
        for (int kk = 0; kk < 2; ++kk)
            #pragma unroll
            for (int m = 0; m < 2; ++m)
                #pragma unroll
                for (int n = 0; n < NB; ++n)
                    acc[m][n] = __builtin_amdgcn_mfma_f32_16x16x32_bf16(
                        af[m][kk], bfr[n][kk], acc[m][n], 0, 0, 0);
        __syncthreads();
    }

    if constexpr (MODE == 0) {
        if (region < 2) {
            us* sh = (region == 0) ? qs_hi : ks_hi;
            us* slo = (region == 0) ? qs_lo : ks_lo;
            #pragma unroll
            for (int m = 0; m < 2; ++m) {
                const int row = m0 + wr + m * 16 + (l >> 4) * 4;
                #pragma unroll
                for (int n = 0; n < NB; ++n) {
                    const int col = ncol0 + wc + n * 16 + lr;
                    #pragma unroll
                    for (int r = 0; r < 4; ++r) {
                        const float val = acc[m][n][r];
                        const us h = f2bf(val);
                        sh[(size_t)(row + r) * 512 + col] = h;
                        slo[(size_t)(row + r) * 512 + col] = f2bf(val - bf2f(h));
                    }
                }
            }
        } else {
            #pragma unroll
            for (int m = 0; m < 2; ++m) {
                const int row = m0 + wr + m * 16 + (l >> 4) * 4;
                #pragma unroll
                for (int n = 0; n < NB; ++n) {
                    const int col = ncol0 + wc + n * 16 + lr;
                    #pragma unroll
                    for (int r = 0; r < 4; ++r)
                        vb[(size_t)(row + r) * 512 + col] = f2bf(acc[m][n][r]);
                }
            }
        }
    } else {
        #pragma unroll
        for (int m = 0; m < 2; ++m) {
            const int row = m0 + wr + m * 16 + (l >> 4) * 4;
            #pragma unroll
            for (int n = 0; n < NB; ++n) {
                const int col = n0 + wc + n * 16 + lr;
                #pragma unroll
                for (int r = 0; r < 4; ++r)
                    cout[(size_t)(row + r) * 512 + col] = acc[m][n][r];
            }
        }
    }
}

// ---------------------------------------------------------------------------
// w12 GEMM (BK=64 XOR-swizzled, K'=384 = 6 steps — same proven pattern as the
// QKV kernel) grid-packed with V colsum. Blocks 0..383: w12; 384..415: colsum.
// w1[b,hh,i,l] = q[b,i,(hh+1)*128+:] . kn[b*4+hh+1,l,:]   (z=0)
// w2t[b,hh,j,l] = k[b,j,(hh+1)*128+:] . qn[b*4+hh+1,l,:]  (z=1)
// ---------------------------------------------------------------------------
__global__ __launch_bounds__(256) void k_w12_colsum(
    const us* __restrict__ q_hi, const us* __restrict__ q_lo,
    const us* __restrict__ k_hi, const us* __restrict__ k_lo,
    const us* __restrict__ kn_hi, const us* __restrict__ kn_lo,
    const us* __restrict__ qn_hi, const us* __restrict__ qn_lo,
    float* __restrict__ w1, float* __restrict__ w2t,
    const us* __restrict__ vb, float* __restrict__ cs)
{
    const int blk = blockIdx.x;
    const int tid = threadIdx.x;
    if (blk >= 384) {                           // ---- colsum part ----
        const int c4 = tid * 4;                 // 0..1023 (b*512 + c)
        const int b = c4 >> 9, c = c4 & 511;
        const int t0 = (blk - 384) * 64;
        const us* p = vb + ((size_t)(b * TT + t0)) * NX + c;
        f32x4 s = {0.f, 0.f, 0.f, 0.f};
        for (int t = 0; t < 64; ++t) {
            const ushort4 u = *reinterpret_cast<const ushort4*>(p + (size_t)t * NX);
            s[0] += bf2f(u.x); s[1] += bf2f(u.y); s[2] += bf2f(u.z); s[3] += bf2f(u.w);
        }
        atomicAdd(&cs[c4 + 0], s[0]);
        atomicAdd(&cs[c4 + 1], s[1]);
        atomicAdd(&cs[c4 + 2], s[2]);
        atomicAdd(&cs[c4 + 3], s[3]);
        return;
    }
    // ---- w12 part: BK=64 swizzled (QKV-kernel pattern) ----
    __shared__ us lsA[64 * 64];
    __shared__ us lsB[64 * 64];
    const int m0 = (blk & 31) * 64;
    const int y = (blk >> 5) % 6;
    const int z = blk / 192;
    const int hh = y % 3, b = y / 3;
    const int h = hh + 1;
    const us* ah = (z ? k_hi : q_hi) + ((size_t)b * 2048) * 512 + h * 128;
    const us* al = (z ? k_lo : q_lo) + ((size_t)b * 2048) * 512 + h * 128;
    const us* bhp = (z ? qn_hi : kn_hi) + (size_t)(b * 4 + h) * 64 * 128;
    const us* blp = (z ? qn_lo : kn_lo) + (size_t)(b * 4 + h) * 64 * 128;
    float* C = (z ? w2t : w1) + (size_t)(b * 3 + hh) * 2048 * 64;

    const int l = tid & 63, wid = tid >> 6;
    const int wr = (wid >> 1) * 32, wc = (wid & 1) * 32;
    const int lr = l & 15;
    const int lkb = (l >> 4) * 16;
    f32x4 acc[2][2] = {};
    const int r8 = tid >> 3;
    const int swzc8 = (((tid & 7) ^ (r8 & 7)) * 8);

    for (int kt = 0; kt < 6; ++kt) {
        const int seg = kt >> 1;                // 0,0,1,1,2,2
        const int koff = (kt & 1) * 64;         // within 128-col head slice
        const us* ab = (seg < 2 ? ah : al) + koff + swzc8;
        const us* bb = (seg == 1 ? blp : bhp) + koff + swzc8;
        #pragma unroll
        for (int j = 0; j < 2; ++j) {
            __builtin_amdgcn_global_load_lds((gptr_t)(ab + (size_t)(m0 + j * 32 + r8) * 512),
                                             (lptr_t)(lsA + j * 2048 + tid * 8), 16, 0, 0);
            __builtin_amdgcn_global_load_lds((gptr_t)(bb + (size_t)(j * 32 + r8) * 128),
                                             (lptr_t)(lsB + j * 2048 + tid * 8), 16, 0, 0);
        }
        __syncthreads();
        bf16x8 af[2][2], bfr[2][2];
        #pragma unroll
        for (int m = 0; m < 2; ++m) {
            const int row = wr + m * 16 + lr;
            #pragma unroll
            for (int kk = 0; kk < 2; ++kk) {
                const int cb = (kk * 64 + lkb) ^ ((row & 7) << 4);
                af[m][kk] = *reinterpret_cast<const bf16x8*>((const char*)lsA + row * 128 + cb);
            }
        }
        #pragma unroll
        for (int n = 0; n < 2; ++n) {
            const int row = wc + n * 16 + lr;
            #pragma unroll
            for (int kk = 0; kk < 2; ++kk) {
                const int cb = (kk * 64 + lkb) ^ ((row & 7) << 4);
                bfr[n][kk] = *reinterpret_cast<const bf16x8*>((const char*)lsB + row * 128 + cb);
            }
        }
        #pragma unroll
        for (int kk = 0; kk < 2; ++kk)
            #pragma unroll
            for (int m = 0; m < 2; ++m)
                #pragma unroll
                for (int n = 0; n < 2; ++n)
                    acc[m][n] = __builtin_amdgcn_mfma_f32_16x16x32_bf16(
                        af[m][kk], bfr[n][kk], acc[m][n], 0, 0, 0);
        __syncthreads();
    }

    #pragma unroll
    for (int m = 0; m < 2; ++m) {
        const int row = m0 + wr + m * 16 + (l >> 4) * 4;
        #pragma unroll
        for (int n = 0; n < 2; ++n) {
            const int col = wc + n * 16 + lr;
            #pragma unroll
            for (int r = 0; r < 4; ++r)
                C[(size_t)(row + r) * 64 + col] = acc[m][n][r];
        }
    }
}

// Normalized landmark rows -> bf16 hi/lo splits. 4 waves/block, 1 unit/wave.
__global__ __launch_bounds__(256) void k_norm_lm(
    const us* __restrict__ q_hi, const us* __restrict__ q_lo,
    const us* __restrict__ k_hi, const us* __restrict__ k_lo,
    const float* __restrict__ m1, const float* __restrict__ m2,
    const int* __restrict__ landmark,
    us* __restrict__ qn_hi, us* __restrict__ qn_lo,
    us* __restrict__ kn_hi, us* __restrict__ kn_lo)
{
    const int idx = blockIdx.x * 4 + (threadIdx.x >> 6);   // 0..511 = (b,h,l)
    const int l = idx & 63;
    const int h = (idx >> 6) & 3;
    const int b = idx >> 8;
    const int lm = landmark[l];
    const int d = threadIdx.x & 63;

    const size_t qoff = ((size_t)(b * TT + lm)) * NX + h * HD;
    const float qa = bf2f(q_hi[qoff + d]) + bf2f(q_lo[qoff + d]);
    const float qb = bf2f(q_hi[qoff + d + 64]) + bf2f(q_lo[qoff + d + 64]);
    const float ka = bf2f(k_hi[qoff + d]) + bf2f(k_lo[qoff + d]);
    const float kb = bf2f(k_hi[qoff + d + 64]) + bf2f(k_lo[qoff + d + 64]);
    float sq = qa * qa + qb * qb;
    float sk = ka * ka + kb * kb;
    for (int off = 32; off; off >>= 1) { sq += __shfl_xor(sq, off); sk += __shfl_xor(sk, off); }
    const float invq = rsqrtf(sq) * m1[h * LL + l];
    const float invk = rsqrtf(sk) * m2[h * LL + l];
    const size_t base = (((size_t)(b * NH + h)) * LL + l) * HD;
    const float vq0 = qa * invq, vq1 = qb * invq;
    const float vk0 = ka * invk, vk1 = kb * invk;
    us h0;
    h0 = f2bf(vq0); qn_hi[base + d] = h0;      qn_lo[base + d] = f2bf(vq0 - bf2f(h0));
    h0 = f2bf(vq1); qn_hi[base + d + 64] = h0; qn_lo[base + d + 64] = f2bf(vq1 - bf2f(h0));
    h0 = f2bf(vk0); kn_hi[base + d] = h0;      kn_lo[base + d] = f2bf(vk0 - bf2f(h0));
    h0 = f2bf(vk1); kn_hi[base + d + 64] = h0; kn_lo[base + d + 64] = f2bf(vk1 - bf2f(h0));
}

// ---------------------------------------------------------------------------
// Sparse masked softmax + wmix + PV + RMSNorm. ONE WAVE per (b, row i);
// wave-synchronous. 4 independent waves per block. V bf16; ao plain bf16.
// ---------------------------------------------------------------------------
__global__ __launch_bounds__(256) void k_sparse_attn(
    const float* __restrict__ w1, const float* __restrict__ w2t,
    const us* __restrict__ vb, const float* __restrict__ cs,
    const int* __restrict__ rns, const float* __restrict__ rms_g,
    const float* __restrict__ scal,
    us* __restrict__ ao)
{
    const int wid = threadIdx.x >> 6;
    const int lane = threadIdx.x & 63;
    const int bi = blockIdx.x * 4 + wid;     // 0..4095
    const int b = bi >> 11, i = bi & 2047;

    __shared__ int   sl[4][32];
    __shared__ float plog[4][96];
    __shared__ float wmm[4][2][32];
    __shared__ float w1s[4][3][64];

    // candidates + dedup + symmetric check
    const int myidx = lane & 31;
    const int cand = rns[(size_t)bi * KK + myidx];
    int dup = 0;
    #pragma unroll
    for (int kk = 0; kk < 31; ++kk) {
        const int other = __shfl(cand, kk);
        dup |= (kk < myidx) & (other == cand);
    }
    const int* jrow = rns + ((size_t)(b * TT + cand)) * KK + (lane >> 5) * 16;
    int found = 0;
    #pragma unroll
    for (int kk = 0; kk < 16; ++kk) found |= (jrow[kk] == i);
    found |= __shfl_xor(found, 32);
    const int keep = (!dup) && found;
    const unsigned long long mask = __ballot(keep) & 0xffffffffull;
    const int sc = __popcll(mask);
    const int pos = __popcll(mask & ((1ull << myidx) - 1ull));
    if (lane < 32 && keep) sl[wid][pos] = cand;

    const float lam = scal[0], lam_init = scal[1];

    if (sc > 0) {
        // stage w1 rows (heads 1..3 compact) for row i
        #pragma unroll
        for (int r = 0; r < 3; ++r)
            w1s[wid][r][lane] = w1[(((size_t)(b * 3 + r)) * TT + i) * LL + lane];
        // logits: tasks t = ss*3 + hh, 8 lanes per task
        const int ntask = 3 * sc;
        for (int t0 = 0; t0 < ntask; t0 += 8) {
            const int t = t0 + (lane >> 3);
            float part = 0.f;
            if (t < ntask) {
                const int hh = t % 3, ss = t / 3;
                const int j = sl[wid][ss];
                const float* w2row = w2t + (((size_t)(b * 3 + hh)) * TT + j) * LL + (lane & 7) * 8;
                const float* w1p = &w1s[wid][hh][(lane & 7) * 8];
                #pragma unroll
                for (int e = 0; e < 8; ++e) part += w1p[e] * w2row[e];
            }
            part += __shfl_xor(part, 1);
            part += __shfl_xor(part, 2);
            part += __shfl_xor(part, 4);
            if (t < ntask && (lane & 7) == 0) plog[wid][t] = part;
        }
        // per-head softmax over sc entries
        if (lane < 3) {
            float mx = -1e30f;
            for (int ss = 0; ss < sc; ++ss) mx = fmaxf(mx, plog[wid][ss * 3 + lane]);
            float s = 0.f;
            for (int ss = 0; ss < sc; ++ss) {
                const float e = expf(plog[wid][ss * 3 + lane] - mx);
                plog[wid][ss * 3 + lane] = e;
                s += e;
            }
            const float inv = 1.0f / s;
            for (int ss = 0; ss < sc; ++ss) plog[wid][ss * 3 + lane] *= inv;
        }
        if (lane < sc) {
            const float p1 = plog[wid][lane * 3 + 0];
            const float p2 = plog[wid][lane * 3 + 1];
            const float p3 = plog[wid][lane * 3 + 2];
            wmm[wid][0][lane] = (1.0f - lam) * p2 - lam * p1;
            wmm[wid][1][lane] = p2 - p1 + (1.0f - 2.0f * lam) * p3;
        }
    }

    // PV: each lane owns cols [lane*4, lane*4+4) of both 256-halves
    f32x4 acc0 = {0.f, 0.f, 0.f, 0.f}, acc1 = {0.f, 0.f, 0.f, 0.f};
    if (sc == 0) {
        const float cc = (1.0f - 2.0f * lam) * (1.0f / (float)TT);
        const f32x4 c0 = *reinterpret_cast<const f32x4*>(cs + b * NX + lane * 4);
        const f32x4 c1 = *reinterpret_cast<const f32x4*>(cs + b * NX + 256 + lane * 4);
        acc0 = cc * c0;
        acc1 = cc * c1;
    } else {
        for (int ss = 0; ss < sc; ++ss) {
            const float wa = wmm[wid][0][ss], wb = wmm[wid][1][ss];
            const us* vrow = vb + ((size_t)(b * TT + sl[wid][ss])) * NX;
            const ushort4 ua = *reinterpret_cast<const ushort4*>(vrow + lane * 4);
            const ushort4 ub = *reinterpret_cast<const ushort4*>(vrow + 256 + lane * 4);
            acc0[0] += wa * bf2f(ua.x); acc0[1] += wa * bf2f(ua.y);
            acc0[2] += wa * bf2f(ua.z); acc0[3] += wa * bf2f(ua.w);
            acc1[0] += wb * bf2f(ub.x); acc1[1] += wb * bf2f(ub.y);
            acc1[2] += wb * bf2f(ub.z); acc1[3] += wb * bf2f(ub.w);
        }
    }

    // RMSNorm per half
    float s0 = acc0[0]*acc0[0] + acc0[1]*acc0[1] + acc0[2]*acc0[2] + acc0[3]*acc0[3];
    float s1 = acc1[0]*acc1[0] + acc1[1]*acc1[1] + acc1[2]*acc1[2] + acc1[3]*acc1[3];
    #pragma unroll
    for (int off = 32; off; off >>= 1) { s0 += __shfl_xor(s0, off); s1 += __shfl_xor(s1, off); }
    const float sc0 = rsqrtf(s0 * (1.0f / 256.0f) + 1e-5f);
    const float sc1 = rsqrtf(s1 * (1.0f / 256.0f) + 1e-5f);
    const float og = 1.0f - lam_init;
    // rms_g (256,) broadcasts over the last axis: BOTH halves use rms_g[e]
    const f32x4 g = *reinterpret_cast<const f32x4*>(rms_g + lane * 4);
    ushort4 h0, h1;
    #pragma unroll
    for (int e = 0; e < 4; ++e) {
        (&h0.x)[e] = f2bf(acc0[e] * sc0 * g[e] * og);
        (&h1.x)[e] = f2bf(acc1[e] * sc1 * g[e] * og);
    }
    *reinterpret_cast<ushort4*>(ao + (size_t)bi * NX + lane * 4) = h0;
    *reinterpret_cast<ushort4*>(ao + (size_t)bi * NX + 256 + lane * 4) = h1;
}

extern "C" void kernel_launch(void* const* d_in, const int* in_sizes, int n_in,
                              void* d_out, int out_size, void* d_ws, size_t ws_size,
                              hipStream_t stream)
{
    const float* x    = (const float*)d_in[0];
    const float* wq   = (const float*)d_in[1];
    const float* wk   = (const float*)d_in[2];
    const float* wv   = (const float*)d_in[3];
    const float* wo   = (const float*)d_in[4];
    const float* m1   = (const float*)d_in[5];
    const float* m2   = (const float*)d_in[6];
    const float* lq1  = (const float*)d_in[7];
    const float* lk1  = (const float*)d_in[8];
    const float* lq2  = (const float*)d_in[9];
    const float* lk2  = (const float*)d_in[10];
    const float* rmsg = (const float*)d_in[11];
    const int*   lint = (const int*)d_in[12];
    const int*   rns  = (const int*)d_in[14];
    const int*   lmk  = (const int*)d_in[15];
    float* out = (float*)d_out;
    float* ws  = (float*)d_ws;

    // ---- workspace layout ----
    const size_t M2 = 2097152;   // 2M elements
    const size_t W3 = 786432;    // (b*3+hh)*2048*64
    float* w1   = ws;                        // 786,432 f32
    float* w2t  = ws + W3;                   // 786,432 f32
    float* cs   = ws + 2 * W3;               // 1,024 f32
    float* scal = cs + 1024;                 // small (pad 128)
    us* S = (us*)(scal + 128);
    us* vb   = S;                  // 2M us (bf16 V)
    us* x_hi = S + M2;             // 2M each
    us* x_lo = S + 2 * M2;
    us* ao   = x_hi;               // reuse (x split dead after QKV); plain bf16
    us* q_hi = S + 3 * M2;
    us* q_lo = S + 4 * M2;
    us* k_hi = S + 5 * M2;
    us* k_lo = S + 6 * M2;
    us* wqkv_hi = S + 7 * M2;              // 786,432
    us* wqkv_lo = wqkv_hi + 786432;
    us* wo_hi = wqkv_lo + 786432;          // 262,144
    us* wo_lo = wo_hi + 262144;
    us* qn_hi = wo_lo + 262144;            // 65,536 each
    us* qn_lo = qn_hi + 65536;
    us* kn_hi = qn_lo + 65536;
    us* kn_lo = kn_hi + 65536;

    k_split_all<<<3073, 256, 0, stream>>>(x, wq, wk, wv, wo,
                                          x_hi, x_lo, wqkv_hi, wqkv_lo, wo_hi, wo_lo,
                                          lq1, lk1, lq2, lk2, lint, scal, cs);

    // QKV fused: M=4096, N=1536 (q|k|v); q/k 3-term -> bf16 splits, v 2-term -> bf16
    k_gemm_big<128, 0><<<dim3(64, 12), 256, 0, stream>>>(
        x_hi, x_lo, wqkv_hi, wqkv_lo, vb, nullptr, q_hi, q_lo, k_hi, k_lo);

    k_norm_lm<<<128, 256, 0, stream>>>(q_hi, q_lo, k_hi, k_lo, m1, m2, lmk,
                                       qn_hi, qn_lo, kn_hi, kn_lo);
    k_w12_colsum<<<416, 256, 0, stream>>>(q_hi, q_lo, k_hi, k_lo,
                                          kn_hi, kn_lo, qn_hi, qn_lo, w1, w2t, vb, cs);
    k_sparse_attn<<<1024, 256, 0, stream>>>(w1, w2t, vb, cs, rns, rmsg, scal, ao);

    // out = ao @ wo^T: M=4096, N=512, 1-seg (K'=512)
    k_gemm_big<64, 1><<<dim3(64, 8), 256, 0, stream>>>(
        ao, nullptr, wo_hi, nullptr, nullptr, out, nullptr, nullptr, nullptr, nullptr);
}

// Round 12
// 139.372 us; speedup vs baseline: 1.2286x; 1.0099x over previous
//
#include <hip/hip_runtime.h>
#include <hip/hip_bf16.h>

// Problem constants
#define BB 2
#define TT 2048
#define NX 512
#define NH 4      // 2*H
#define HD 128
#define LL 64
#define KK 32

typedef __bf16 bf16x8 __attribute__((ext_vector_type(8)));
typedef float f32x4 __attribute__((ext_vector_type(4)));
typedef unsigned short us;
typedef const unsigned int __attribute__((address_space(1)))* gptr_t;
typedef unsigned int __attribute__((address_space(3)))* lptr_t;

__device__ __forceinline__ us f2bf(float f) {
    unsigned u = __float_as_uint(f);
    unsigned r = (u + 0x7fffu + ((u >> 16) & 1u)) >> 16;   // RNE
    return (us)r;
}
__device__ __forceinline__ float bf2f(us h) {
    return __uint_as_float(((unsigned)h) << 16);
}

// ---------------------------------------------------------------------------
// Fused: split f32 -> (hi,lo) bf16 for x,wq,wk,wv,wo  +  lam scalars + cs zero
// ---------------------------------------------------------------------------
__global__ void k_split_all(const float* __restrict__ x,
                            const float* __restrict__ wq, const float* __restrict__ wk,
                            const float* __restrict__ wv, const float* __restrict__ wo,
                            us* __restrict__ x_hi, us* __restrict__ x_lo,
                            us* __restrict__ wqkv_hi, us* __restrict__ wqkv_lo,
                            us* __restrict__ wo_hi, us* __restrict__ wo_lo,
                            const float* __restrict__ lq1, const float* __restrict__ lk1,
                            const float* __restrict__ lq2, const float* __restrict__ lk2,
                            const int* __restrict__ lint, float* __restrict__ scal,
                            float* __restrict__ cs)
{
    const int bidx = blockIdx.x;
    if (bidx == 3072) {                       // lam scalars + cs zeroing
        const int tid = threadIdx.x;
        const f32x4 z = {0.f, 0.f, 0.f, 0.f};
        *reinterpret_cast<f32x4*>(cs + tid * 4) = z;   // 256*4 = 1024 floats
        if (tid < 64) {
            float s1 = lq1[tid] * lk1[tid] + lq1[tid + 64] * lk1[tid + 64];
            float s2 = lq2[tid] * lk2[tid] + lq2[tid + 64] * lk2[tid + 64];
            for (int off = 32; off; off >>= 1) { s1 += __shfl_xor(s1, off); s2 += __shfl_xor(s2, off); }
            if (tid == 0) {
                float lam_init = 0.8f - 0.6f * expf(-0.3f * (float)lint[0]);
                scal[0] = expf(s1) - expf(s2) + lam_init;
                scal[1] = lam_init;
            }
        }
        return;
    }
    const float* src;
    us* hi;
    us* lo;
    int pos;
    if (bidx < 2048) {
        src = x; hi = x_hi; lo = x_lo;
        pos = bidx * 1024 + threadIdx.x * 4;
    } else {
        const int w = (bidx - 2048) >> 8;          // 0..3
        const int p = (bidx - 2048) & 255;
        pos = p * 1024 + threadIdx.x * 4;
        if (w == 0)      { src = wq; hi = wqkv_hi;          lo = wqkv_lo; }
        else if (w == 1) { src = wk; hi = wqkv_hi + 262144; lo = wqkv_lo + 262144; }
        else if (w == 2) { src = wv; hi = wqkv_hi + 524288; lo = wqkv_lo + 524288; }
        else             { src = wo; hi = wo_hi;            lo = wo_lo; }
    }
    const float4 v = *reinterpret_cast<const float4*>(src + pos);
    ushort4 h, l;
    h.x = f2bf(v.x); l.x = f2bf(v.x - bf2f(h.x));
    h.y = f2bf(v.y); l.y = f2bf(v.y - bf2f(h.y));
    h.z = f2bf(v.z); l.z = f2bf(v.z - bf2f(h.z));
    h.w = f2bf(v.w); l.w = f2bf(v.w - bf2f(h.w));
    *reinterpret_cast<ushort4*>(hi + pos) = h;
    *reinterpret_cast<ushort4*>(lo + pos) = l;
}

// ---------------------------------------------------------------------------
// Split-bf16 MFMA GEMM, BM=64, BK=64, XOR-swizzled LDS, SINGLE buffer
// (stage -> sync -> compute -> sync; proven round-6/8 structure).
// MODE 0 (QKV, BN=64, grid y=24): region 0 (q, y 0..7): 3 segs
//   A{hi,hi,lo} B{hi,lo,hi} -> bf16 hi/lo splits;
//   region 1 (k, y 8..15): 2 segs (a_hi+a_lo).b_hi -> bf16 hi/lo splits;
//   region 2 (v, y 16..23): 2 segs -> plain bf16.
// MODE 1 (OUT, BN=64): 1 seg a_hi.b_hi (K'=512), f32 out.
// ---------------------------------------------------------------------------
template<int BN, int MODE>
__global__ __launch_bounds__(256) void k_gemm_big(
    const us* __restrict__ a_hi, const us* __restrict__ a_lo,
    const us* __restrict__ b_hi, const us* __restrict__ b_lo,
    us* __restrict__ vb, float* __restrict__ cout,
    us* __restrict__ qs_hi, us* __restrict__ qs_lo,
    us* __restrict__ ks_hi, us* __restrict__ ks_lo)
{
    constexpr int NB = BN / 32;                 // frag cols per wave
    __shared__ us lsA[64 * 64];
    __shared__ us lsB[BN * 64];
    const int tid = threadIdx.x;
    const int m0 = blockIdx.x * 64, n0 = blockIdx.y * BN;
    const int region = n0 >> 9;                 // 0:q 1:k 2:v (MODE 0)
    const int ncol0 = n0 & 511;
    const int l = tid & 63, wid = tid >> 6;
    const int wr = (wid >> 1) * 32, wc = (wid & 1) * (BN / 2);
    const int lr = l & 15;
    const int lkb = (l >> 4) * 16;              // byte offset of lane's k-octet
    f32x4 acc[2][NB] = {};

    const int r8 = tid >> 3;                    // staging row 0..31
    const int swzc8 = (((tid & 7) ^ (r8 & 7)) * 8);  // pre-swizzled col (shorts)

    const int nstep = (MODE == 0) ? (region == 0 ? 24 : 16) : 8;
    for (int kt = 0; kt < nstep; ++kt) {
        const int seg = kt >> 3;
        const int koff = (kt & 7) * 64;
        const us* ab;
        const us* bb;
        if constexpr (MODE == 0) {
            if (region == 0) {                  // q: 3-term
                ab = (seg < 2 ? a_hi : a_lo) + koff + swzc8;
                bb = (seg == 1 ? b_lo : b_hi) + koff + swzc8;
            } else {   // k, v: (a_hi + a_lo) . b_hi
                ab = (seg == 0 ? a_hi : a_lo) + koff + swzc8;
                bb = b_hi + koff + swzc8;
            }
        } else {       // out: a_hi . b_hi only
            ab = a_hi + koff + swzc8;
            bb = b_hi + koff + swzc8;
        }
        #pragma unroll
        for (int j = 0; j < 2; ++j)
            __builtin_amdgcn_global_load_lds((gptr_t)(ab + (size_t)(m0 + j * 32 + r8) * 512),
                                             (lptr_t)(lsA + j * 2048 + tid * 8), 16, 0, 0);
        #pragma unroll
        for (int j = 0; j < BN / 32; ++j)
            __builtin_amdgcn_global_load_lds((gptr_t)(bb + (size_t)(n0 + j * 32 + r8) * 512),
                                             (lptr_t)(lsB + j * 2048 + tid * 8), 16, 0, 0);
        __syncthreads();   // barrier drains vmcnt -> LDS writes visible
        bf16x8 af[2][2], bfr[NB][2];
        #pragma unroll
        for (int m = 0; m < 2; ++m) {
            const int row = wr + m * 16 + lr;
            #pragma unroll
            for (int kk = 0; kk < 2; ++kk) {
                const int cb = (kk * 64 + lkb) ^ ((row & 7) << 4);
                af[m][kk] = *reinterpret_cast<const bf16x8*>(
                    (const char*)lsA + row * 128 + cb);
            }
        }
        #pragma unroll
        for (int n = 0; n < NB; ++n) {
            const int row = wc + n * 16 + lr;
            #pragma unroll
            for (int kk = 0; kk < 2; ++kk) {
                const int cb = (kk * 64 + lkb) ^ ((row & 7) << 4);
                bfr[n][kk] = *reinterpret_cast<const bf16x8*>(
                    (const char*)lsB + row * 128 + cb);
            }
        }
        #pragma unroll
        for (int kk = 0; kk < 2; ++kk)
            #pragma unroll
            for (int m = 0; m < 2; ++m)
                #pragma unroll
                for (int n = 0; n < NB; ++n)
                    acc[m][n] = __builtin_amdgcn_mfma_f32_16x16x32_bf16(
                        af[m][kk], bfr[n][kk], acc[m][n], 0, 0, 0);
        __syncthreads();
    }

    if constexpr (MODE == 0) {
        if (region < 2) {
            us* sh = (region == 0) ? qs_hi : ks_hi;
            us* slo = (region == 0) ? qs_lo : ks_lo;
            #pragma unroll
            for (int m = 0; m < 2; ++m) {
                const int row = m0 + wr + m * 16 + (l >> 4) * 4;
                #pragma unroll
                for (int n = 0; n < NB; ++n) {
                    const int col = ncol0 + wc + n * 16 + lr;
                    #pragma unroll
                    for (int r = 0; r < 4; ++r) {
                        const float val = acc[m][n][r];
                        const us h = f2bf(val);
                        sh[(size_t)(row + r) * 512 + col] = h;
                        slo[(size_t)(row + r) * 512 + col] = f2bf(val - bf2f(h));
                    }
                }
            }
        } else {
            #pragma unroll
            for (int m = 0; m < 2; ++m) {
                const int row = m0 + wr + m * 16 + (l >> 4) * 4;
                #pragma unroll
                for (int n = 0; n < NB; ++n) {
                    const int col = ncol0 + wc + n * 16 + lr;
                    #pragma unroll
                    for (int r = 0; r < 4; ++r)
                        vb[(size_t)(row + r) * 512 + col] = f2bf(acc[m][n][r]);
                }
            }
        }
    } else {
        #pragma unroll
        for (int m = 0; m < 2; ++m) {
            const int row = m0 + wr + m * 16 + (l >> 4) * 4;
            #pragma unroll
            for (int n = 0; n < NB; ++n) {
                const int col = n0 + wc + n * 16 + lr;
                #pragma unroll
                for (int r = 0; r < 4; ++r)
                    cout[(size_t)(row + r) * 512 + col] = acc[m][n][r];
            }
        }
    }
}

// ---------------------------------------------------------------------------
// w12 GEMM (BK=64 XOR-swizzled, K'=384 = 6 steps) grid-packed with V colsum.
// Blocks 0..383: w12; 384..415: colsum.
// w1[b,hh,i,l] = q[b,i,(hh+1)*128+:] . kn[b*4+hh+1,l,:]   (z=0)
// w2t[b,hh,j,l] = k[b,j,(hh+1)*128+:] . qn[b*4+hh+1,l,:]  (z=1)
// ---------------------------------------------------------------------------
__global__ __launch_bounds__(256) void k_w12_colsum(
    const us* __restrict__ q_hi, const us* __restrict__ q_lo,
    const us* __restrict__ k_hi, const us* __restrict__ k_lo,
    const us* __restrict__ kn_hi, const us* __restrict__ kn_lo,
    const us* __restrict__ qn_hi, const us* __restrict__ qn_lo,
    float* __restrict__ w1, float* __restrict__ w2t,
    const us* __restrict__ vb, float* __restrict__ cs)
{
    const int blk = blockIdx.x;
    const int tid = threadIdx.x;
    if (blk >= 384) {                           // ---- colsum part ----
        const int c4 = tid * 4;                 // 0..1023 (b*512 + c)
        const int b = c4 >> 9, c = c4 & 511;
        const int t0 = (blk - 384) * 64;
        const us* p = vb + ((size_t)(b * TT + t0)) * NX + c;
        f32x4 s = {0.f, 0.f, 0.f, 0.f};
        for (int t = 0; t < 64; ++t) {
            const ushort4 u = *reinterpret_cast<const ushort4*>(p + (size_t)t * NX);
            s[0] += bf2f(u.x); s[1] += bf2f(u.y); s[2] += bf2f(u.z); s[3] += bf2f(u.w);
        }
        atomicAdd(&cs[c4 + 0], s[0]);
        atomicAdd(&cs[c4 + 1], s[1]);
        atomicAdd(&cs[c4 + 2], s[2]);
        atomicAdd(&cs[c4 + 3], s[3]);
        return;
    }
    // ---- w12 part: BK=64 swizzled (QKV-kernel pattern) ----
    __shared__ us lsA[64 * 64];
    __shared__ us lsB[64 * 64];
    const int m0 = (blk & 31) * 64;
    const int y = (blk >> 5) % 6;
    const int z = blk / 192;
    const int hh = y % 3, b = y / 3;
    const int h = hh + 1;
    const us* ah = (z ? k_hi : q_hi) + ((size_t)b * 2048) * 512 + h * 128;
    const us* al = (z ? k_lo : q_lo) + ((size_t)b * 2048) * 512 + h * 128;
    const us* bhp = (z ? qn_hi : kn_hi) + (size_t)(b * 4 + h) * 64 * 128;
    const us* blp = (z ? qn_lo : kn_lo) + (size_t)(b * 4 + h) * 64 * 128;
    float* C = (z ? w2t : w1) + (size_t)(b * 3 + hh) * 2048 * 64;

    const int l = tid & 63, wid = tid >> 6;
    const int wr = (wid >> 1) * 32, wc = (wid & 1) * 32;
    const int lr = l & 15;
    const int lkb = (l >> 4) * 16;
    f32x4 acc[2][2] = {};
    const int r8 = tid >> 3;
    const int swzc8 = (((tid & 7) ^ (r8 & 7)) * 8);

    for (int kt = 0; kt < 6; ++kt) {
        const int seg = kt >> 1;                // 0,0,1,1,2,2
        const int koff = (kt & 1) * 64;         // within 128-col head slice
        const us* ab = (seg < 2 ? ah : al) + koff + swzc8;
        const us* bb = (seg == 1 ? blp : bhp) + koff + swzc8;
        #pragma unroll
        for (int j = 0; j < 2; ++j) {
            __builtin_amdgcn_global_load_lds((gptr_t)(ab + (size_t)(m0 + j * 32 + r8) * 512),
                                             (lptr_t)(lsA + j * 2048 + tid * 8), 16, 0, 0);
            __builtin_amdgcn_global_load_lds((gptr_t)(bb + (size_t)(j * 32 + r8) * 128),
                                             (lptr_t)(lsB + j * 2048 + tid * 8), 16, 0, 0);
        }
        __syncthreads();
        bf16x8 af[2][2], bfr[2][2];
        #pragma unroll
        for (int m = 0; m < 2; ++m) {
            const int row = wr + m * 16 + lr;
            #pragma unroll
            for (int kk = 0; kk < 2; ++kk) {
                const int cb = (kk * 64 + lkb) ^ ((row & 7) << 4);
                af[m][kk] = *reinterpret_cast<const bf16x8*>((const char*)lsA + row * 128 + cb);
            }
        }
        #pragma unroll
        for (int n = 0; n < 2; ++n) {
            const int row = wc + n * 16 + lr;
            #pragma unroll
            for (int kk = 0; kk < 2; ++kk) {
                const int cb = (kk * 64 + lkb) ^ ((row & 7) << 4);
                bfr[n][kk] = *reinterpret_cast<const bf16x8*>((const char*)lsB + row * 128 + cb);
            }
        }
        #pragma unroll
        for (int kk = 0; kk < 2; ++kk)
            #pragma unroll
            for (int m = 0; m < 2; ++m)
                #pragma unroll
                for (int n = 0; n < 2; ++n)
                    acc[m][n] = __builtin_amdgcn_mfma_f32_16x16x32_bf16(
                        af[m][kk], bfr[n][kk], acc[m][n], 0, 0, 0);
        __syncthreads();
    }

    #pragma unroll
    for (int m = 0; m < 2; ++m) {
        const int row = m0 + wr + m * 16 + (l >> 4) * 4;
        #pragma unroll
        for (int n = 0; n < 2; ++n) {
            const int col = wc + n * 16 + lr;
            #pragma unroll
            for (int r = 0; r < 4; ++r)
                C[(size_t)(row + r) * 64 + col] = acc[m][n][r];
        }
    }
}

// Normalized landmark rows -> bf16 hi/lo splits. 4 waves/block, 1 unit/wave.
__global__ __launch_bounds__(256) void k_norm_lm(
    const us* __restrict__ q_hi, const us* __restrict__ q_lo,
    const us* __restrict__ k_hi, const us* __restrict__ k_lo,
    const float* __restrict__ m1, const float* __restrict__ m2,
    const int* __restrict__ landmark,
    us* __restrict__ qn_hi, us* __restrict__ qn_lo,
    us* __restrict__ kn_hi, us* __restrict__ kn_lo)
{
    const int idx = blockIdx.x * 4 + (threadIdx.x >> 6);   // 0..511 = (b,h,l)
    const int l = idx & 63;
    const int h = (idx >> 6) & 3;
    const int b = idx >> 8;
    const int lm = landmark[l];
    const int d = threadIdx.x & 63;

    const size_t qoff = ((size_t)(b * TT + lm)) * NX + h * HD;
    const float qa = bf2f(q_hi[qoff + d]) + bf2f(q_lo[qoff + d]);
    const float qb = bf2f(q_hi[qoff + d + 64]) + bf2f(q_lo[qoff + d + 64]);
    const float ka = bf2f(k_hi[qoff + d]) + bf2f(k_lo[qoff + d]);
    const float kb = bf2f(k_hi[qoff + d + 64]) + bf2f(k_lo[qoff + d + 64]);
    float sq = qa * qa + qb * qb;
    float sk = ka * ka + kb * kb;
    for (int off = 32; off; off >>= 1) { sq += __shfl_xor(sq, off); sk += __shfl_xor(sk, off); }
    const float invq = rsqrtf(sq) * m1[h * LL + l];
    const float invk = rsqrtf(sk) * m2[h * LL + l];
    const size_t base = (((size_t)(b * NH + h)) * LL + l) * HD;
    const float vq0 = qa * invq, vq1 = qb * invq;
    const float vk0 = ka * invk, vk1 = kb * invk;
    us h0;
    h0 = f2bf(vq0); qn_hi[base + d] = h0;      qn_lo[base + d] = f2bf(vq0 - bf2f(h0));
    h0 = f2bf(vq1); qn_hi[base + d + 64] = h0; qn_lo[base + d + 64] = f2bf(vq1 - bf2f(h0));
    h0 = f2bf(vk0); kn_hi[base + d] = h0;      kn_lo[base + d] = f2bf(vk0 - bf2f(h0));
    h0 = f2bf(vk1); kn_hi[base + d + 64] = h0; kn_lo[base + d + 64] = f2bf(vk1 - bf2f(h0));
}

// ---------------------------------------------------------------------------
// Sparse masked softmax + wmix + PV + RMSNorm. ONE WAVE per (b, row i);
// wave-synchronous. 4 independent waves per block. V bf16; ao plain bf16.
// ---------------------------------------------------------------------------
__global__ __launch_bounds__(256) void k_sparse_attn(
    const float* __restrict__ w1, const float* __restrict__ w2t,
    const us* __restrict__ vb, const float* __restrict__ cs,
    const int* __restrict__ rns, const float* __restrict__ rms_g,
    const float* __restrict__ scal,
    us* __restrict__ ao)
{
    const int wid = threadIdx.x >> 6;
    const int lane = threadIdx.x & 63;
    const int bi = blockIdx.x * 4 + wid;     // 0..4095
    const int b = bi >> 11, i = bi & 2047;

    __shared__ int   sl[4][32];
    __shared__ float plog[4][96];
    __shared__ float wmm[4][2][32];
    __shared__ float w1s[4][3][64];

    // candidates + dedup + symmetric check
    const int myidx = lane & 31;
    const int cand = rns[(size_t)bi * KK + myidx];
    int dup = 0;
    #pragma unroll
    for (int kk = 0; kk < 31; ++kk) {
        const int other = __shfl(cand, kk);
        dup |= (kk < myidx) & (other == cand);
    }
    const int* jrow = rns + ((size_t)(b * TT + cand)) * KK + (lane >> 5) * 16;
    int found = 0;
    #pragma unroll
    for (int kk = 0; kk < 16; ++kk) found |= (jrow[kk] == i);
    found |= __shfl_xor(found, 32);
    const int keep = (!dup) && found;
    const unsigned long long mask = __ballot(keep) & 0xffffffffull;
    const int sc = __popcll(mask);
    const int pos = __popcll(mask & ((1ull << myidx) - 1ull));
    if (lane < 32 && keep) sl[wid][pos] = cand;

    const float lam = scal[0], lam_init = scal[1];

    if (sc > 0) {
        // stage w1 rows (heads 1..3 compact) for row i
        #pragma unroll
        for (int r = 0; r < 3; ++r)
            w1s[wid][r][lane] = w1[(((size_t)(b * 3 + r)) * TT + i) * LL + lane];
        // logits: tasks t = ss*3 + hh, 8 lanes per task
        const int ntask = 3 * sc;
        for (int t0 = 0; t0 < ntask; t0 += 8) {
            const int t = t0 + (lane >> 3);
            float part = 0.f;
            if (t < ntask) {
                const int hh = t % 3, ss = t / 3;
                const int j = sl[wid][ss];
                const float* w2row = w2t + (((size_t)(b * 3 + hh)) * TT + j) * LL + (lane & 7) * 8;
                const float* w1p = &w1s[wid][hh][(lane & 7) * 8];
                #pragma unroll
                for (int e = 0; e < 8; ++e) part += w1p[e] * w2row[e];
            }
            part += __shfl_xor(part, 1);
            part += __shfl_xor(part, 2);
            part += __shfl_xor(part, 4);
            if (t < ntask && (lane & 7) == 0) plog[wid][t] = part;
        }
        // per-head softmax over sc entries
        if (lane < 3) {
            float mx = -1e30f;
            for (int ss = 0; ss < sc; ++ss) mx = fmaxf(mx, plog[wid][ss * 3 + lane]);
            float s = 0.f;
            for (int ss = 0; ss < sc; ++ss) {
                const float e = expf(plog[wid][ss * 3 + lane] - mx);
                plog[wid][ss * 3 + lane] = e;
                s += e;
            }
            const float inv = 1.0f / s;
            for (int ss = 0; ss < sc; ++ss) plog[wid][ss * 3 + lane] *= inv;
        }
        if (lane < sc) {
            const float p1 = plog[wid][lane * 3 + 0];
            const float p2 = plog[wid][lane * 3 + 1];
            const float p3 = plog[wid][lane * 3 + 2];
            wmm[wid][0][lane] = (1.0f - lam) * p2 - lam * p1;
            wmm[wid][1][lane] = p2 - p1 + (1.0f - 2.0f * lam) * p3;
        }
    }

    // PV: each lane owns cols [lane*4, lane*4+4) of both 256-halves
    f32x4 acc0 = {0.f, 0.f, 0.f, 0.f}, acc1 = {0.f, 0.f, 0.f, 0.f};
    if (sc == 0) {
        const float cc = (1.0f - 2.0f * lam) * (1.0f / (float)TT);
        const f32x4 c0 = *reinterpret_cast<const f32x4*>(cs + b * NX + lane * 4);
        const f32x4 c1 = *reinterpret_cast<const f32x4*>(cs + b * NX + 256 + lane * 4);
        acc0 = cc * c0;
        acc1 = cc * c1;
    } else {
        for (int ss = 0; ss < sc; ++ss) {
            const float wa = wmm[wid][0][ss], wb = wmm[wid][1][ss];
            const us* vrow = vb + ((size_t)(b * TT + sl[wid][ss])) * NX;
            const ushort4 ua = *reinterpret_cast<const ushort4*>(vrow + lane * 4);
            const ushort4 ub = *reinterpret_cast<const ushort4*>(vrow + 256 + lane * 4);
            acc0[0] += wa * bf2f(ua.x); acc0[1] += wa * bf2f(ua.y);
            acc0[2] += wa * bf2f(ua.z); acc0[3] += wa * bf2f(ua.w);
            acc1[0] += wb * bf2f(ub.x); acc1[1] += wb * bf2f(ub.y);
            acc1[2] += wb * bf2f(ub.z); acc1[3] += wb * bf2f(ub.w);
        }
    }

    // RMSNorm per half
    float s0 = acc0[0]*acc0[0] + acc0[1]*acc0[1] + acc0[2]*acc0[2] + acc0[3]*acc0[3];
    float s1 = acc1[0]*acc1[0] + acc1[1]*acc1[1] + acc1[2]*acc1[2] + acc1[3]*acc1[3];
    #pragma unroll
    for (int off = 32; off; off >>= 1) { s0 += __shfl_xor(s0, off); s1 += __shfl_xor(s1, off); }
    const float sc0 = rsqrtf(s0 * (1.0f / 256.0f) + 1e-5f);
    const float sc1 = rsqrtf(s1 * (1.0f / 256.0f) + 1e-5f);
    const float og = 1.0f - lam_init;
    // rms_g (256,) broadcasts over the last axis: BOTH halves use rms_g[e]
    const f32x4 g = *reinterpret_cast<const f32x4*>(rms_g + lane * 4);
    ushort4 h0, h1;
    #pragma unroll
    for (int e = 0; e < 4; ++e) {
        (&h0.x)[e] = f2bf(acc0[e] * sc0 * g[e] * og);
        (&h1.x)[e] = f2bf(acc1[e] * sc1 * g[e] * og);
    }
    *reinterpret_cast<ushort4*>(ao + (size_t)bi * NX + lane * 4) = h0;
    *reinterpret_cast<ushort4*>(ao + (size_t)bi * NX + 256 + lane * 4) = h1;
}

extern "C" void kernel_launch(void* const* d_in, const int* in_sizes, int n_in,
                              void* d_out, int out_size, void* d_ws, size_t ws_size,
                              hipStream_t stream)
{
    const float* x    = (const float*)d_in[0];
    const float* wq   = (const float*)d_in[1];
    const float* wk   = (const float*)d_in[2];
    const float* wv   = (const float*)d_in[3];
    const float* wo   = (const float*)d_in[4];
    const float* m1   = (const float*)d_in[5];
    const float* m2   = (const float*)d_in[6];
    const float* lq1  = (const float*)d_in[7];
    const float* lk1  = (const float*)d_in[8];
    const float* lq2  = (const float*)d_in[9];
    const float* lk2  = (const float*)d_in[10];
    const float* rmsg = (const float*)d_in[11];
    const int*   lint = (const int*)d_in[12];
    const int*   rns  = (const int*)d_in[14];
    const int*   lmk  = (const int*)d_in[15];
    float* out = (float*)d_out;
    float* ws  = (float*)d_ws;

    // ---- workspace layout ----
    const size_t M2 = 2097152;   // 2M elements
    const size_t W3 = 786432;    // (b*3+hh)*2048*64
    float* w1   = ws;                        // 786,432 f32
    float* w2t  = ws + W3;                   // 786,432 f32
    float* cs   = ws + 2 * W3;               // 1,024 f32
    float* scal = cs + 1024;                 // small (pad 128)
    us* S = (us*)(scal + 128);
    us* vb   = S;                  // 2M us (bf16 V)
    us* x_hi = S + M2;             // 2M each
    us* x_lo = S + 2 * M2;
    us* ao   = x_hi;               // reuse (x split dead after QKV); plain bf16
    us* q_hi = S + 3 * M2;
    us* q_lo = S + 4 * M2;
    us* k_hi = S + 5 * M2;
    us* k_lo = S + 6 * M2;
    us* wqkv_hi = S + 7 * M2;              // 786,432
    us* wqkv_lo = wqkv_hi + 786432;
    us* wo_hi = wqkv_lo + 786432;          // 262,144
    us* wo_lo = wo_hi + 262144;
    us* qn_hi = wo_lo + 262144;            // 65,536 each
    us* qn_lo = qn_hi + 65536;
    us* kn_hi = qn_lo + 65536;
    us* kn_lo = kn_hi + 65536;

    k_split_all<<<3073, 256, 0, stream>>>(x, wq, wk, wv, wo,
                                          x_hi, x_lo, wqkv_hi, wqkv_lo, wo_hi, wo_lo,
                                          lq1, lk1, lq2, lk2, lint, scal, cs);

    // QKV fused: M=4096, N=1536 (q|k|v), BN=64 -> 1536 blocks (6/CU);
    // q 3-term, k 2-term, v 2-term; q/k emit bf16 splits, v plain bf16
    k_gemm_big<64, 0><<<dim3(64, 24), 256, 0, stream>>>(
        x_hi, x_lo, wqkv_hi, wqkv_lo, vb, nullptr, q_hi, q_lo, k_hi, k_lo);

    k_norm_lm<<<128, 256, 0, stream>>>(q_hi, q_lo, k_hi, k_lo, m1, m2, lmk,
                                       qn_hi, qn_lo, kn_hi, kn_lo);
    k_w12_colsum<<<416, 256, 0, stream>>>(q_hi, q_lo, k_hi, k_lo,
                                          kn_hi, kn_lo, qn_hi, qn_lo, w1, w2t, vb, cs);
    k_sparse_attn<<<1024, 256, 0, stream>>>(w1, w2t, vb, cs, rns, rmsg, scal, ao);

    // out = ao @ wo^T: M=4096, N=512, 1-seg (K'=512)
    k_gemm_big<64, 1><<<dim3(64, 8), 256, 0, stream>>>(
        ao, nullptr, wo_hi, nullptr, nullptr, out, nullptr, nullptr, nullptr, nullptr);
}